// Round 4
// baseline (504.784 us; speedup 1.0000x reference)
//
#include <hip/hip_runtime.h>
#include <hip/hip_bf16.h>

#define NUM_NODES 50000
#define DIM 64
#define NUM_EDGES 800000
#define NUM_GRAPHS 3
#define TOT_NODES (NUM_NODES * NUM_GRAPHS)      // 150000
#define TOT_EDGES (NUM_EDGES * NUM_GRAPHS)      // 2400000
#define EPS 1e-12f
#define SCAN_BLK 256
#define NUM_CHUNKS ((TOT_NODES + SCAN_BLK - 1) / SCAN_BLK)   // 586

typedef unsigned short ushort_t;
typedef unsigned int uint_t;

__device__ __forceinline__ float bf2f(ushort_t u) {
    return __uint_as_float(((uint_t)u) << 16);
}
__device__ __forceinline__ ushort_t f2bf(float f) {
    uint_t x = __float_as_uint(f);
    uint_t r = (x + 0x7FFFu + ((x >> 16) & 1u)) >> 16;   // RNE
    return (ushort_t)r;
}

// ---------------- L2 normalize input -> bf16 shared table ----------------
__global__ void l2norm_kernel(const float* __restrict__ in, ushort_t* __restrict__ out) {
    int row = blockIdx.x * (blockDim.x >> 6) + (threadIdx.x >> 6);
    int lane = threadIdx.x & 63;
    if (row >= NUM_NODES) return;
    float v = in[(long)row * DIM + lane];
    float s = v * v;
    #pragma unroll
    for (int off = 32; off > 0; off >>= 1)
        s += __shfl_xor(s, off, 64);
    float inv = 1.0f / fmaxf(sqrtf(s), EPS);
    out[(long)row * DIM + lane] = f2bf(v * inv);
}

// ---------------- histogram of dst for all 3 graphs ----------------
__global__ void hist3_kernel(const int* __restrict__ e0, const int* __restrict__ e1,
                             const int* __restrict__ e2, int* __restrict__ cnt) {
    int e = blockIdx.x * blockDim.x + threadIdx.x;
    int g = blockIdx.y;
    if (e >= NUM_EDGES) return;
    const int* dst = ((g == 0) ? e0 : (g == 1) ? e1 : e2) + NUM_EDGES;
    atomicAdd(&cnt[g * NUM_NODES + dst[e]], 1);
}

// ---------------- scan stage 1: per-chunk sums over 150000 counts ----------------
__global__ void scan_partials_kernel(const int* __restrict__ cnt, int* __restrict__ partial) {
    int t = threadIdx.x;
    int i = blockIdx.x * SCAN_BLK + t;
    int v = (i < TOT_NODES) ? cnt[i] : 0;
    #pragma unroll
    for (int off = 32; off > 0; off >>= 1)
        v += __shfl_xor(v, off, 64);
    __shared__ int sw[4];
    if ((t & 63) == 0) sw[t >> 6] = v;
    __syncthreads();
    if (t == 0) partial[blockIdx.x] = sw[0] + sw[1] + sw[2] + sw[3];
}

// ---------------- scan stage 2: exclusive-scan 586 partials (1 block of 1024) ----------------
__global__ void scan_single_kernel(const int* __restrict__ partial, int* __restrict__ pscan) {
    int t = threadIdx.x;
    int v = (t < NUM_CHUNKS) ? partial[t] : 0;
    __shared__ int sd[1024];
    sd[t] = v;
    __syncthreads();
    #pragma unroll
    for (int off = 1; off < 1024; off <<= 1) {
        int add = (t >= off) ? sd[t - off] : 0;
        __syncthreads();
        sd[t] += add;
        __syncthreads();
    }
    if (t < NUM_CHUNKS) pscan[t] = sd[t] - v;   // exclusive
}

// ---------------- scan stage 3: per-chunk exclusive scan + offset ----------------
__global__ void scan_apply_kernel(const int* __restrict__ cnt, const int* __restrict__ pscan,
                                  int* __restrict__ row_start) {
    int t = threadIdx.x;
    int i = blockIdx.x * SCAN_BLK + t;
    int v = (i < TOT_NODES) ? cnt[i] : 0;
    __shared__ int sd[SCAN_BLK];
    sd[t] = v;
    __syncthreads();
    #pragma unroll
    for (int off = 1; off < SCAN_BLK; off <<= 1) {
        int add = (t >= off) ? sd[t - off] : 0;
        __syncthreads();
        sd[t] += add;
        __syncthreads();
    }
    if (i < TOT_NODES) row_start[i] = pscan[blockIdx.x] + sd[t] - v;
    if (i == 0) row_start[TOT_NODES] = TOT_EDGES;
}

// ---------------- prep: dinv from degree (cnt); cursor = row_start copy ----------------
__global__ void prep_kernel(const int* __restrict__ cnt, const int* __restrict__ row_start,
                            float* __restrict__ dinv, int* __restrict__ cursor) {
    int i = blockIdx.x * blockDim.x + threadIdx.x;
    if (i >= TOT_NODES) return;
    int deg = cnt[i];
    dinv[i] = (deg > 0) ? rsqrtf((float)deg) : 0.0f;
    cursor[i] = row_start[i];
}

// ---------------- scatter src indices (ushort) into concatenated CSR ----------------
__global__ void scatter3_kernel(const int* __restrict__ e0, const int* __restrict__ e1,
                                const int* __restrict__ e2,
                                int* __restrict__ cursor,
                                ushort_t* __restrict__ esort) {
    int e = blockIdx.x * blockDim.x + threadIdx.x;
    int g = blockIdx.y;
    if (e >= NUM_EDGES) return;
    const int* ei = (g == 0) ? e0 : (g == 1) ? e1 : e2;
    int s = ei[e];
    int t = ei[NUM_EDGES + e];
    int pos = atomicAdd(&cursor[g * NUM_NODES + t], 1);
    esort[pos] = (ushort_t)s;
}

// ---------------- layer 1, all 3 graphs: b[t] = dinv_t^2 * sum dinv_s * xn[s] ----------------
__global__ void conv1_all_kernel(const ushort_t* __restrict__ xn,
                                 const ushort_t* __restrict__ esort,
                                 const int* __restrict__ row_start,
                                 const float* __restrict__ dinv,
                                 ushort_t* __restrict__ bufA) {
    int row = blockIdx.x * (blockDim.x >> 6) + (threadIdx.x >> 6);
    int lane = threadIdx.x & 63;
    if (row >= NUM_NODES) return;
    #pragma unroll
    for (int g = 0; g < NUM_GRAPHS; ++g) {
        int k = g * NUM_NODES + row;
        int start = __builtin_amdgcn_readfirstlane(row_start[k]);
        int end   = __builtin_amdgcn_readfirstlane(row_start[k + 1]);
        const float* dv = dinv + g * NUM_NODES;
        float acc = 0.0f;
        int i = start;
        for (; i + 4 <= end; i += 4) {
            int s0 = esort[i];
            int s1 = esort[i + 1];
            int s2 = esort[i + 2];
            int s3 = esort[i + 3];
            float d0 = dv[s0], d1 = dv[s1], d2 = dv[s2], d3 = dv[s3];
            float v0 = bf2f(xn[(long)s0 * DIM + lane]);
            float v1 = bf2f(xn[(long)s1 * DIM + lane]);
            float v2 = bf2f(xn[(long)s2 * DIM + lane]);
            float v3 = bf2f(xn[(long)s3 * DIM + lane]);
            acc += d0 * v0;
            acc += d1 * v1;
            acc += d2 * v2;
            acc += d3 * v3;
        }
        for (; i < end; ++i) {
            int s = esort[i];
            acc += dv[s] * bf2f(xn[(long)s * DIM + lane]);
        }
        float dt = dinv[k];
        bufA[(long)k * DIM + lane] = f2bf(acc * dt * dt);
    }
}

// ---------------- layer 2 (pure sum) + l2norm + weighted blend -> out ----------------
__global__ void conv2_finalize_kernel(const ushort_t* __restrict__ bufA,
                                      const ushort_t* __restrict__ esort,
                                      const int* __restrict__ row_start,
                                      const float* __restrict__ alpha,
                                      float* __restrict__ out) {
    int row = blockIdx.x * (blockDim.x >> 6) + (threadIdx.x >> 6);
    int lane = threadIdx.x & 63;
    if (row >= NUM_NODES) return;

    // softmax(alpha) -> clip -> renormalize
    float a0 = alpha[0], a1 = alpha[1], a2 = alpha[2];
    float m = fmaxf(a0, fmaxf(a1, a2));
    float e0 = expf(a0 - m), e1 = expf(a1 - m), e2 = expf(a2 - m);
    float es = e0 + e1 + e2;
    float w0 = fmaxf(e0 / es, 1e-4f);
    float w1 = fmaxf(e1 / es, 1e-4f);
    float w2 = fmaxf(e2 / es, 1e-4f);
    float ws = w0 + w1 + w2;

    float res = 0.0f;
    #pragma unroll
    for (int g = 0; g < NUM_GRAPHS; ++g) {
        int k = g * NUM_NODES + row;
        int start = __builtin_amdgcn_readfirstlane(row_start[k]);
        int end   = __builtin_amdgcn_readfirstlane(row_start[k + 1]);
        const ushort_t* tbl = bufA + (long)g * NUM_NODES * DIM;
        float acc = 0.0f;
        int i = start;
        for (; i + 4 <= end; i += 4) {
            int s0 = esort[i];
            int s1 = esort[i + 1];
            int s2 = esort[i + 2];
            int s3 = esort[i + 3];
            float v0 = bf2f(tbl[(long)s0 * DIM + lane]);
            float v1 = bf2f(tbl[(long)s1 * DIM + lane]);
            float v2 = bf2f(tbl[(long)s2 * DIM + lane]);
            float v3 = bf2f(tbl[(long)s3 * DIM + lane]);
            acc += v0;
            acc += v1;
            acc += v2;
            acc += v3;
        }
        for (; i < end; ++i) {
            int s = esort[i];
            acc += bf2f(tbl[(long)s * DIM + lane]);
        }

        // dinv[t] row-scale cancels under L2 normalization
        float s = acc * acc;
        #pragma unroll
        for (int off = 32; off > 0; off >>= 1)
            s += __shfl_xor(s, off, 64);
        float inv = 1.0f / fmaxf(sqrtf(s), EPS);
        float w = ((g == 0) ? w0 : (g == 1) ? w1 : w2) / ws;
        res += w * acc * inv;
    }

    out[(long)row * DIM + lane] = res;
}

extern "C" void kernel_launch(void* const* d_in, const int* in_sizes, int n_in,
                              void* d_out, int out_size, void* d_ws, size_t ws_size,
                              hipStream_t stream) {
    const float* x     = (const float*)d_in[0];
    const float* alpha = (const float*)d_in[1];
    const int* e0 = (const int*)d_in[2];
    const int* e1 = (const int*)d_in[3];
    const int* e2 = (const int*)d_in[4];
    float* out = (float*)d_out;

    // workspace layout (~32 MB)
    ushort_t* xn   = (ushort_t*)d_ws;                          // 50000*64 bf16   (6.4 MB)
    ushort_t* bufA = xn + (long)NUM_NODES * DIM;               // 150000*64 bf16  (19.2 MB)
    float* dinv    = (float*)(bufA + (long)TOT_NODES * DIM);   // 150000 f32
    int* cnt       = (int*)(dinv + TOT_NODES);                 // 150000 (reused as cursor)
    int* row_start = cnt + TOT_NODES;                          // 150001 (pad to 150008)
    int* partial   = row_start + 150008;                       // 1024
    int* pscan     = partial + 1024;                           // 1024
    ushort_t* esort = (ushort_t*)(pscan + 1024);               // 2400000 ushort  (4.8 MB)

    const int wave_grid = (NUM_NODES * 64 + 255) / 256;        // 1 wave/row, 4 waves/block
    const int edge_blocks = (NUM_EDGES + 255) / 256;
    const int tnode_grid = (TOT_NODES + 255) / 256;

    // normalize input once (f32 -> bf16 shared table)
    l2norm_kernel<<<wave_grid, 256, 0, stream>>>(x, xn);

    // ---- build concatenated CSR for all 3 graphs ----
    hipMemsetAsync(cnt, 0, TOT_NODES * sizeof(int), stream);
    {
        dim3 grd(edge_blocks, NUM_GRAPHS);
        hist3_kernel<<<grd, 256, 0, stream>>>(e0, e1, e2, cnt);
    }
    scan_partials_kernel<<<NUM_CHUNKS, SCAN_BLK, 0, stream>>>(cnt, partial);
    scan_single_kernel<<<1, 1024, 0, stream>>>(partial, pscan);
    scan_apply_kernel<<<NUM_CHUNKS, SCAN_BLK, 0, stream>>>(cnt, pscan, row_start);
    prep_kernel<<<tnode_grid, 256, 0, stream>>>(cnt, row_start, dinv, cnt /*cursor (in place)*/);
    {
        dim3 grd(edge_blocks, NUM_GRAPHS);
        scatter3_kernel<<<grd, 256, 0, stream>>>(e0, e1, e2, cnt /*cursor*/, esort);
    }

    // ---- layer 1 (all graphs) ----
    conv1_all_kernel<<<wave_grid, 256, 0, stream>>>(xn, esort, row_start, dinv, bufA);
    // ---- layer 2 + normalize + blend (all graphs) ----
    conv2_finalize_kernel<<<wave_grid, 256, 0, stream>>>(bufA, esort, row_start, alpha, out);
}

// Round 5
// 319.987 us; speedup vs baseline: 1.5775x; 1.5775x over previous
//
#include <hip/hip_runtime.h>
#include <hip/hip_bf16.h>

#define NUM_NODES 50000
#define DIM 64
#define NUM_EDGES 800000
#define NUM_GRAPHS 3
#define TOT_NODES (NUM_NODES * NUM_GRAPHS)      // 150000
#define TOT_EDGES (NUM_EDGES * NUM_GRAPHS)      // 2400000
#define EPS 1e-12f

#define NB 196                                   // buckets per graph: dst>>8 (50000/256 -> 196)
#define TB (NB * NUM_GRAPHS)                     // 588 total buckets
#define P3_CHUNK 8192
#define P3_BLOCKS ((NUM_EDGES + P3_CHUNK - 1) / P3_CHUNK)   // 98
#define P4_CAP 6144                              // max records per bucket (mean 4096, sigma ~64)

typedef unsigned short ushort_t;
typedef unsigned int uint_t;

__device__ __forceinline__ float bf2f(ushort_t u) {
    return __uint_as_float(((uint_t)u) << 16);
}
__device__ __forceinline__ ushort_t f2bf(float f) {
    uint_t x = __float_as_uint(f);
    uint_t r = (x + 0x7FFFu + ((x >> 16) & 1u)) >> 16;   // RNE
    return (ushort_t)r;
}

// ---------------- L2 normalize input -> bf16 shared table ----------------
__global__ void l2norm_kernel(const float* __restrict__ in, ushort_t* __restrict__ out) {
    int row = blockIdx.x * (blockDim.x >> 6) + (threadIdx.x >> 6);
    int lane = threadIdx.x & 63;
    if (row >= NUM_NODES) return;
    float v = in[(long)row * DIM + lane];
    float s = v * v;
    #pragma unroll
    for (int off = 32; off > 0; off >>= 1)
        s += __shfl_xor(s, off, 64);
    float inv = 1.0f / fmaxf(sqrtf(s), EPS);
    out[(long)row * DIM + lane] = f2bf(v * inv);
}

// ---------------- P1: coarse histogram (LDS-binned) ----------------
__global__ void hist_coarse_kernel(const int* __restrict__ e0, const int* __restrict__ e1,
                                   const int* __restrict__ e2, int* __restrict__ bhist) {
    int g = blockIdx.y;
    const int* dst = ((g == 0) ? e0 : (g == 1) ? e1 : e2) + NUM_EDGES;
    __shared__ int h[NB];
    int t = threadIdx.x;
    for (int i = t; i < NB; i += 256) h[i] = 0;
    __syncthreads();
    int base = blockIdx.x * P3_CHUNK;
    int n = min(P3_CHUNK, NUM_EDGES - base);
    for (int i = t; i < n; i += 256)
        atomicAdd(&h[dst[base + i] >> 8], 1);
    __syncthreads();
    for (int i = t; i < NB; i += 256)
        if (h[i]) atomicAdd(&bhist[g * NB + i], h[i]);
}

// ---------------- P2: exclusive-scan 588 bucket counts (1 block) ----------------
__global__ void bucket_scan_kernel(const int* __restrict__ bhist, int* __restrict__ bbase,
                                   int* __restrict__ bcur) {
    int t = threadIdx.x;
    int v = (t < TB) ? bhist[t] : 0;
    __shared__ int sd[1024];
    sd[t] = v;
    __syncthreads();
    #pragma unroll
    for (int off = 1; off < 1024; off <<= 1) {
        int add = (t >= off) ? sd[t - off] : 0;
        __syncthreads();
        sd[t] += add;
        __syncthreads();
    }
    if (t < TB) {
        int ex = sd[t] - v;
        bbase[t] = ex;
        bcur[t] = ex;
    }
    if (t == 0) bbase[TB] = TOT_EDGES;
}

// ---------------- P3: partition edges into buckets, LDS-staged coalesced writes ----------------
__global__ void partition_kernel(const int* __restrict__ e0, const int* __restrict__ e1,
                                 const int* __restrict__ e2,
                                 int* __restrict__ bcur, uint_t* __restrict__ part) {
    __shared__ uint_t recs[P3_CHUNK];        // 32 KB
    __shared__ int h[NB], lstart[NB], gbase[NB], lcur[NB];
    __shared__ int sc[256];

    int g = blockIdx.y;
    const int* ei = (g == 0) ? e0 : (g == 1) ? e1 : e2;
    const int* srcp = ei;
    const int* dstp = ei + NUM_EDGES;
    int base = blockIdx.x * P3_CHUNK;
    int n = min(P3_CHUNK, NUM_EDGES - base);
    int t = threadIdx.x;

    for (int i = t; i < NB; i += 256) h[i] = 0;
    __syncthreads();
    for (int i = t; i < n; i += 256)
        atomicAdd(&h[dstp[base + i] >> 8], 1);
    __syncthreads();

    // block scan over NB (<=256) with 256 threads
    {
        int v = (t < NB) ? h[t] : 0;
        sc[t] = v;
        __syncthreads();
        #pragma unroll
        for (int off = 1; off < 256; off <<= 1) {
            int add = (t >= off) ? sc[t - off] : 0;
            __syncthreads();
            sc[t] += add;
            __syncthreads();
        }
        if (t < NB) {
            int ex = sc[t] - v;
            lstart[t] = ex;
            lcur[t] = ex;
            gbase[t] = (v > 0) ? atomicAdd(&bcur[g * NB + t], v) : 0;
        }
    }
    __syncthreads();

    // place records into LDS, bucket-sorted
    for (int i = t; i < n; i += 256) {
        int s = srcp[base + i];
        int d = dstp[base + i];
        int pos = atomicAdd(&lcur[d >> 8], 1);
        recs[pos] = ((uint_t)d << 16) | (uint_t)s;
    }
    __syncthreads();

    // stream out: consecutive LDS slots -> consecutive global slots per bucket segment
    for (int i = t; i < n; i += 256) {
        uint_t r = recs[i];
        int b = r >> 24;                      // dst>>8 (dst < 2^16)
        part[gbase[b] + (i - lstart[b])] = r;
    }
}

// ---------------- P4: per-bucket fine sort -> esort + row_start + dinv ----------------
__global__ void bucket_sort_kernel(const uint_t* __restrict__ part, const int* __restrict__ bbase,
                                   ushort_t* __restrict__ esort, int* __restrict__ row_start,
                                   float* __restrict__ dinv) {
    __shared__ uint_t recs[P4_CAP];          // 24 KB
    __shared__ int rstart[256], lcur[256];
    __shared__ int sc[256];

    int b = blockIdx.x;                       // 0..TB-1
    int g = b / NB;
    int bhi = b % NB;
    int s0 = bbase[b];
    int n = bbase[b + 1] - s0;
    int t = threadIdx.x;

    sc[t] = 0;   // reuse sc as histogram first
    __syncthreads();
    for (int i = t; i < n; i += 256) {
        uint_t r = part[s0 + i];
        recs[i] = r;
        atomicAdd(&sc[(r >> 16) & 255], 1);
    }
    __syncthreads();
    int v = sc[t];
    __syncthreads();
    // scan 256
    sc[t] = v;
    __syncthreads();
    #pragma unroll
    for (int off = 1; off < 256; off <<= 1) {
        int add = (t >= off) ? sc[t - off] : 0;
        __syncthreads();
        sc[t] += add;
        __syncthreads();
    }
    int ex = sc[t] - v;
    rstart[t] = ex;
    lcur[t] = ex;

    int node = (bhi << 8) + t;
    if (node < NUM_NODES) {
        row_start[g * NUM_NODES + node] = s0 + ex;
        dinv[g * NUM_NODES + node] = (v > 0) ? rsqrtf((float)v) : 0.0f;
    }
    if (b == TB - 1 && t == 0) row_start[TOT_NODES] = TOT_EDGES;
    __syncthreads();

    for (int i = t; i < n; i += 256) {
        uint_t r = recs[i];
        int dl = (r >> 16) & 255;
        int pos = atomicAdd(&lcur[dl], 1);
        esort[s0 + pos] = (ushort_t)(r & 0xFFFFu);
    }
}

// ---------------- layer 1, all 3 graphs: b[t] = dinv_t^2 * sum dinv_s * xn[s] ----------------
__global__ void conv1_all_kernel(const ushort_t* __restrict__ xn,
                                 const ushort_t* __restrict__ esort,
                                 const int* __restrict__ row_start,
                                 const float* __restrict__ dinv,
                                 ushort_t* __restrict__ bufA) {
    int row = blockIdx.x * (blockDim.x >> 6) + (threadIdx.x >> 6);
    int lane = threadIdx.x & 63;
    if (row >= NUM_NODES) return;
    #pragma unroll
    for (int g = 0; g < NUM_GRAPHS; ++g) {
        int k = g * NUM_NODES + row;
        int start = __builtin_amdgcn_readfirstlane(row_start[k]);
        int end   = __builtin_amdgcn_readfirstlane(row_start[k + 1]);
        const float* dv = dinv + g * NUM_NODES;
        float acc = 0.0f;
        int i = start;
        for (; i + 4 <= end; i += 4) {
            int s0 = esort[i];
            int s1 = esort[i + 1];
            int s2 = esort[i + 2];
            int s3 = esort[i + 3];
            float d0 = dv[s0], d1 = dv[s1], d2 = dv[s2], d3 = dv[s3];
            float v0 = bf2f(xn[(long)s0 * DIM + lane]);
            float v1 = bf2f(xn[(long)s1 * DIM + lane]);
            float v2 = bf2f(xn[(long)s2 * DIM + lane]);
            float v3 = bf2f(xn[(long)s3 * DIM + lane]);
            acc += d0 * v0;
            acc += d1 * v1;
            acc += d2 * v2;
            acc += d3 * v3;
        }
        for (; i < end; ++i) {
            int s = esort[i];
            acc += dv[s] * bf2f(xn[(long)s * DIM + lane]);
        }
        float dt = dinv[k];
        bufA[(long)k * DIM + lane] = f2bf(acc * dt * dt);
    }
}

// ---------------- layer 2 (pure sum) + l2norm + weighted blend -> out ----------------
__global__ void conv2_finalize_kernel(const ushort_t* __restrict__ bufA,
                                      const ushort_t* __restrict__ esort,
                                      const int* __restrict__ row_start,
                                      const float* __restrict__ alpha,
                                      float* __restrict__ out) {
    int row = blockIdx.x * (blockDim.x >> 6) + (threadIdx.x >> 6);
    int lane = threadIdx.x & 63;
    if (row >= NUM_NODES) return;

    // softmax(alpha) -> clip -> renormalize
    float a0 = alpha[0], a1 = alpha[1], a2 = alpha[2];
    float m = fmaxf(a0, fmaxf(a1, a2));
    float e0 = expf(a0 - m), e1 = expf(a1 - m), e2 = expf(a2 - m);
    float es = e0 + e1 + e2;
    float w0 = fmaxf(e0 / es, 1e-4f);
    float w1 = fmaxf(e1 / es, 1e-4f);
    float w2 = fmaxf(e2 / es, 1e-4f);
    float ws = w0 + w1 + w2;

    float res = 0.0f;
    #pragma unroll
    for (int g = 0; g < NUM_GRAPHS; ++g) {
        int k = g * NUM_NODES + row;
        int start = __builtin_amdgcn_readfirstlane(row_start[k]);
        int end   = __builtin_amdgcn_readfirstlane(row_start[k + 1]);
        const ushort_t* tbl = bufA + (long)g * NUM_NODES * DIM;
        float acc = 0.0f;
        int i = start;
        for (; i + 4 <= end; i += 4) {
            int s0 = esort[i];
            int s1 = esort[i + 1];
            int s2 = esort[i + 2];
            int s3 = esort[i + 3];
            float v0 = bf2f(tbl[(long)s0 * DIM + lane]);
            float v1 = bf2f(tbl[(long)s1 * DIM + lane]);
            float v2 = bf2f(tbl[(long)s2 * DIM + lane]);
            float v3 = bf2f(tbl[(long)s3 * DIM + lane]);
            acc += v0;
            acc += v1;
            acc += v2;
            acc += v3;
        }
        for (; i < end; ++i) {
            int s = esort[i];
            acc += bf2f(tbl[(long)s * DIM + lane]);
        }

        // dinv[t] row-scale cancels under L2 normalization
        float s = acc * acc;
        #pragma unroll
        for (int off = 32; off > 0; off >>= 1)
            s += __shfl_xor(s, off, 64);
        float inv = 1.0f / fmaxf(sqrtf(s), EPS);
        float w = ((g == 0) ? w0 : (g == 1) ? w1 : w2) / ws;
        res += w * acc * inv;
    }

    out[(long)row * DIM + lane] = res;
}

extern "C" void kernel_launch(void* const* d_in, const int* in_sizes, int n_in,
                              void* d_out, int out_size, void* d_ws, size_t ws_size,
                              hipStream_t stream) {
    const float* x     = (const float*)d_in[0];
    const float* alpha = (const float*)d_in[1];
    const int* e0 = (const int*)d_in[2];
    const int* e1 = (const int*)d_in[3];
    const int* e2 = (const int*)d_in[4];
    float* out = (float*)d_out;

    // workspace layout (~41 MB)
    ushort_t* xn   = (ushort_t*)d_ws;                          // 50000*64 bf16   (6.4 MB)
    ushort_t* bufA = xn + (long)NUM_NODES * DIM;               // 150000*64 bf16  (19.2 MB)
    float* dinv    = (float*)(bufA + (long)TOT_NODES * DIM);   // 150000 f32
    int* row_start = (int*)(dinv + TOT_NODES);                 // 150001 (pad to 150016)
    int* bhist     = row_start + 150016;                       // 640
    int* bbase     = bhist + 640;                              // 640 (TB+1 used)
    int* bcur      = bbase + 640;                              // 640
    uint_t* part   = (uint_t*)(bcur + 640);                    // 2400000 u32     (9.6 MB)
    ushort_t* esort = (ushort_t*)(part + TOT_EDGES);           // 2400000 u16     (4.8 MB)

    const int wave_grid = (NUM_NODES * 64 + 255) / 256;        // 1 wave/row, 4 waves/block

    // normalize input once (f32 -> bf16 shared table)
    l2norm_kernel<<<wave_grid, 256, 0, stream>>>(x, xn);

    // ---- build concatenated CSR via 2-pass bucketed counting sort ----
    hipMemsetAsync(bhist, 0, TB * sizeof(int), stream);
    {
        dim3 grd(P3_BLOCKS, NUM_GRAPHS);
        hist_coarse_kernel<<<grd, 256, 0, stream>>>(e0, e1, e2, bhist);
    }
    bucket_scan_kernel<<<1, 1024, 0, stream>>>(bhist, bbase, bcur);
    {
        dim3 grd(P3_BLOCKS, NUM_GRAPHS);
        partition_kernel<<<grd, 256, 0, stream>>>(e0, e1, e2, bcur, part);
    }
    bucket_sort_kernel<<<TB, 256, 0, stream>>>(part, bbase, esort, row_start, dinv);

    // ---- layer 1 (all graphs) ----
    conv1_all_kernel<<<wave_grid, 256, 0, stream>>>(xn, esort, row_start, dinv, bufA);
    // ---- layer 2 + normalize + blend (all graphs) ----
    conv2_finalize_kernel<<<wave_grid, 256, 0, stream>>>(bufA, esort, row_start, alpha, out);
}

// Round 6
// 270.821 us; speedup vs baseline: 1.8639x; 1.1815x over previous
//
#include <hip/hip_runtime.h>
#include <hip/hip_bf16.h>

#define NUM_NODES 50000
#define DIM 64
#define NUM_EDGES 800000
#define NUM_GRAPHS 3
#define TOT_NODES (NUM_NODES * NUM_GRAPHS)      // 150000
#define TOT_EDGES (NUM_EDGES * NUM_GRAPHS)      // 2400000
#define EPS 1e-12f

#define NB 196                                   // buckets per graph: dst>>8
#define TB (NB * NUM_GRAPHS)                     // 588 total buckets
#define P3_CHUNK 8192
#define P3_BLOCKS ((NUM_EDGES + P3_CHUNK - 1) / P3_CHUNK)   // 98
#define P4_CAP 6144                              // max records per bucket (mean 4096)

typedef unsigned short ushort_t;
typedef unsigned int uint_t;
typedef unsigned short ushort4v __attribute__((ext_vector_type(4)));   // 8 B

__device__ __forceinline__ float bf2f(ushort_t u) {
    return __uint_as_float(((uint_t)u) << 16);
}
__device__ __forceinline__ ushort_t f2bf(float f) {
    uint_t x = __float_as_uint(f);
    uint_t r = (x + 0x7FFFu + ((x >> 16) & 1u)) >> 16;   // RNE
    return (ushort_t)r;
}

// ---------------- L2 normalize input -> bf16 shared table ----------------
__global__ void l2norm_kernel(const float* __restrict__ in, ushort_t* __restrict__ out) {
    int row = blockIdx.x * (blockDim.x >> 6) + (threadIdx.x >> 6);
    int lane = threadIdx.x & 63;
    if (row >= NUM_NODES) return;
    float v = in[(long)row * DIM + lane];
    float s = v * v;
    #pragma unroll
    for (int off = 32; off > 0; off >>= 1)
        s += __shfl_xor(s, off, 64);
    float inv = 1.0f / fmaxf(sqrtf(s), EPS);
    out[(long)row * DIM + lane] = f2bf(v * inv);
}

// ---------------- P1: coarse histogram (LDS-binned) ----------------
__global__ void hist_coarse_kernel(const int* __restrict__ e0, const int* __restrict__ e1,
                                   const int* __restrict__ e2, int* __restrict__ bhist) {
    int g = blockIdx.y;
    const int* dst = ((g == 0) ? e0 : (g == 1) ? e1 : e2) + NUM_EDGES;
    __shared__ int h[NB];
    int t = threadIdx.x;
    for (int i = t; i < NB; i += 256) h[i] = 0;
    __syncthreads();
    int base = blockIdx.x * P3_CHUNK;
    int n = min(P3_CHUNK, NUM_EDGES - base);
    for (int i = t; i < n; i += 256)
        atomicAdd(&h[dst[base + i] >> 8], 1);
    __syncthreads();
    for (int i = t; i < NB; i += 256)
        if (h[i]) atomicAdd(&bhist[g * NB + i], h[i]);
}

// ---------------- P2: exclusive-scan 588 bucket counts (1 block) ----------------
__global__ void bucket_scan_kernel(const int* __restrict__ bhist, int* __restrict__ bbase,
                                   int* __restrict__ bcur) {
    int t = threadIdx.x;
    int v = (t < TB) ? bhist[t] : 0;
    __shared__ int sd[1024];
    sd[t] = v;
    __syncthreads();
    #pragma unroll
    for (int off = 1; off < 1024; off <<= 1) {
        int add = (t >= off) ? sd[t - off] : 0;
        __syncthreads();
        sd[t] += add;
        __syncthreads();
    }
    if (t < TB) {
        int ex = sd[t] - v;
        bbase[t] = ex;
        bcur[t] = ex;
    }
    if (t == 0) bbase[TB] = TOT_EDGES;
}

// ---------------- P3: partition edges into buckets, LDS-staged coalesced writes ----------------
__global__ void partition_kernel(const int* __restrict__ e0, const int* __restrict__ e1,
                                 const int* __restrict__ e2,
                                 int* __restrict__ bcur, uint_t* __restrict__ part) {
    __shared__ uint_t recs[P3_CHUNK];        // 32 KB
    __shared__ int h[NB], lstart[NB], gbase[NB], lcur[NB];
    __shared__ int sc[256];

    int g = blockIdx.y;
    const int* ei = (g == 0) ? e0 : (g == 1) ? e1 : e2;
    const int* srcp = ei;
    const int* dstp = ei + NUM_EDGES;
    int base = blockIdx.x * P3_CHUNK;
    int n = min(P3_CHUNK, NUM_EDGES - base);
    int t = threadIdx.x;

    for (int i = t; i < NB; i += 256) h[i] = 0;
    __syncthreads();
    for (int i = t; i < n; i += 256)
        atomicAdd(&h[dstp[base + i] >> 8], 1);
    __syncthreads();

    // block scan over NB (<=256) with 256 threads
    {
        int v = (t < NB) ? h[t] : 0;
        sc[t] = v;
        __syncthreads();
        #pragma unroll
        for (int off = 1; off < 256; off <<= 1) {
            int add = (t >= off) ? sc[t - off] : 0;
            __syncthreads();
            sc[t] += add;
            __syncthreads();
        }
        if (t < NB) {
            int ex = sc[t] - v;
            lstart[t] = ex;
            lcur[t] = ex;
            gbase[t] = (v > 0) ? atomicAdd(&bcur[g * NB + t], v) : 0;
        }
    }
    __syncthreads();

    // place records into LDS, bucket-sorted
    for (int i = t; i < n; i += 256) {
        int s = srcp[base + i];
        int d = dstp[base + i];
        int pos = atomicAdd(&lcur[d >> 8], 1);
        recs[pos] = ((uint_t)d << 16) | (uint_t)s;
    }
    __syncthreads();

    // stream out: consecutive LDS slots -> consecutive global slots per bucket segment
    for (int i = t; i < n; i += 256) {
        uint_t r = recs[i];
        int b = r >> 24;                      // dst>>8 (dst < 2^16)
        part[gbase[b] + (i - lstart[b])] = r;
    }
}

// ---------------- P4: per-bucket fine sort -> esort + row_start + dinv ----------------
__global__ void bucket_sort_kernel(const uint_t* __restrict__ part, const int* __restrict__ bbase,
                                   ushort_t* __restrict__ esort, int* __restrict__ row_start,
                                   float* __restrict__ dinv) {
    __shared__ uint_t recs[P4_CAP];          // 24 KB
    __shared__ int rstart[256], lcur[256];
    __shared__ int sc[256];

    int b = blockIdx.x;                       // 0..TB-1
    int g = b / NB;
    int bhi = b % NB;
    int s0 = bbase[b];
    int n = bbase[b + 1] - s0;
    int t = threadIdx.x;

    sc[t] = 0;   // histogram over dst-low
    __syncthreads();
    for (int i = t; i < n; i += 256) {
        uint_t r = part[s0 + i];
        recs[i] = r;
        atomicAdd(&sc[(r >> 16) & 255], 1);
    }
    __syncthreads();
    int v = sc[t];
    __syncthreads();
    sc[t] = v;
    __syncthreads();
    #pragma unroll
    for (int off = 1; off < 256; off <<= 1) {
        int add = (t >= off) ? sc[t - off] : 0;
        __syncthreads();
        sc[t] += add;
        __syncthreads();
    }
    int ex = sc[t] - v;
    rstart[t] = ex;
    lcur[t] = ex;

    int node = (bhi << 8) + t;
    if (node < NUM_NODES) {
        row_start[g * NUM_NODES + node] = s0 + ex;
        dinv[g * NUM_NODES + node] = (v > 0) ? rsqrtf((float)v) : 0.0f;
    }
    if (b == TB - 1 && t == 0) row_start[TOT_NODES] = TOT_EDGES;
    __syncthreads();

    for (int i = t; i < n; i += 256) {
        uint_t r = recs[i];
        int dl = (r >> 16) & 255;
        int pos = atomicAdd(&lcur[dl], 1);
        esort[s0 + pos] = (ushort_t)(r & 0xFFFFu);
    }
}

// ---------------- layer 1, 2D grid (row, g): b[t] = dinv_t^2 * sum dinv_s * xn[s] ----------------
// 16 lanes per row (ushort4/lane); 4 edges in flight per wave, unroll x2 -> 8.
__global__ void conv1_all_kernel(const ushort_t* __restrict__ xn,
                                 const ushort_t* __restrict__ esort,
                                 const int* __restrict__ row_start,
                                 const float* __restrict__ dinv,
                                 ushort_t* __restrict__ bufA) {
    int row = blockIdx.x * (blockDim.x >> 6) + (threadIdx.x >> 6);
    int g = blockIdx.y;
    int lane = threadIdx.x & 63;
    int sub = lane >> 4;
    int li = lane & 15;
    if (row >= NUM_NODES) return;

    int k = g * NUM_NODES + row;
    int start = __builtin_amdgcn_readfirstlane(row_start[k]);
    int end   = __builtin_amdgcn_readfirstlane(row_start[k + 1]);
    const float* dv = dinv + g * NUM_NODES;

    float a0 = 0.0f, a1 = 0.0f, a2 = 0.0f, a3 = 0.0f;
    int i = start;
    for (; i + 8 <= end; i += 8) {
        int sA = esort[i + sub];
        int sB = esort[i + 4 + sub];
        float dA = dv[sA];
        float dB = dv[sB];
        ushort4v rA = *(const ushort4v*)(xn + (long)sA * DIM + li * 4);
        ushort4v rB = *(const ushort4v*)(xn + (long)sB * DIM + li * 4);
        a0 += dA * bf2f(rA[0]); a1 += dA * bf2f(rA[1]);
        a2 += dA * bf2f(rA[2]); a3 += dA * bf2f(rA[3]);
        a0 += dB * bf2f(rB[0]); a1 += dB * bf2f(rB[1]);
        a2 += dB * bf2f(rB[2]); a3 += dB * bf2f(rB[3]);
    }
    for (; i < end; i += 4) {
        int e = i + sub;
        if (e < end) {
            int s = esort[e];
            float d = dv[s];
            ushort4v r = *(const ushort4v*)(xn + (long)s * DIM + li * 4);
            a0 += d * bf2f(r[0]); a1 += d * bf2f(r[1]);
            a2 += d * bf2f(r[2]); a3 += d * bf2f(r[3]);
        }
    }
    // combine the 4 sub-groups (dims are aligned across subs)
    #pragma unroll
    for (int off = 16; off < 64; off <<= 1) {
        a0 += __shfl_xor(a0, off, 64);
        a1 += __shfl_xor(a1, off, 64);
        a2 += __shfl_xor(a2, off, 64);
        a3 += __shfl_xor(a3, off, 64);
    }
    float dt = dinv[k];
    float sc = dt * dt;
    if (sub == 0) {
        ushort4v o;
        o[0] = f2bf(a0 * sc); o[1] = f2bf(a1 * sc);
        o[2] = f2bf(a2 * sc); o[3] = f2bf(a3 * sc);
        *(ushort4v*)(bufA + (long)k * DIM + li * 4) = o;
    }
}

// ---------------- layer 2 (pure sum) + l2norm + weighted blend -> out ----------------
__global__ void conv2_finalize_kernel(const ushort_t* __restrict__ bufA,
                                      const ushort_t* __restrict__ esort,
                                      const int* __restrict__ row_start,
                                      const float* __restrict__ alpha,
                                      float* __restrict__ out) {
    int row = blockIdx.x * (blockDim.x >> 6) + (threadIdx.x >> 6);
    int lane = threadIdx.x & 63;
    int sub = lane >> 4;
    int li = lane & 15;
    if (row >= NUM_NODES) return;

    // softmax(alpha) -> clip -> renormalize
    float al0 = alpha[0], al1 = alpha[1], al2 = alpha[2];
    float m = fmaxf(al0, fmaxf(al1, al2));
    float e0 = expf(al0 - m), e1 = expf(al1 - m), e2 = expf(al2 - m);
    float es = e0 + e1 + e2;
    float w0 = fmaxf(e0 / es, 1e-4f);
    float w1 = fmaxf(e1 / es, 1e-4f);
    float w2 = fmaxf(e2 / es, 1e-4f);
    float ws = w0 + w1 + w2;

    float r0 = 0.0f, r1 = 0.0f, r2 = 0.0f, r3 = 0.0f;
    #pragma unroll
    for (int g = 0; g < NUM_GRAPHS; ++g) {
        int k = g * NUM_NODES + row;
        int start = __builtin_amdgcn_readfirstlane(row_start[k]);
        int end   = __builtin_amdgcn_readfirstlane(row_start[k + 1]);
        const ushort_t* tbl = bufA + (long)g * NUM_NODES * DIM;

        float a0 = 0.0f, a1 = 0.0f, a2 = 0.0f, a3 = 0.0f;
        int i = start;
        for (; i + 8 <= end; i += 8) {
            int sA = esort[i + sub];
            int sB = esort[i + 4 + sub];
            ushort4v rA = *(const ushort4v*)(tbl + (long)sA * DIM + li * 4);
            ushort4v rB = *(const ushort4v*)(tbl + (long)sB * DIM + li * 4);
            a0 += bf2f(rA[0]); a1 += bf2f(rA[1]);
            a2 += bf2f(rA[2]); a3 += bf2f(rA[3]);
            a0 += bf2f(rB[0]); a1 += bf2f(rB[1]);
            a2 += bf2f(rB[2]); a3 += bf2f(rB[3]);
        }
        for (; i < end; i += 4) {
            int e = i + sub;
            if (e < end) {
                int s = esort[e];
                ushort4v r = *(const ushort4v*)(tbl + (long)s * DIM + li * 4);
                a0 += bf2f(r[0]); a1 += bf2f(r[1]);
                a2 += bf2f(r[2]); a3 += bf2f(r[3]);
            }
        }
        #pragma unroll
        for (int off = 16; off < 64; off <<= 1) {
            a0 += __shfl_xor(a0, off, 64);
            a1 += __shfl_xor(a1, off, 64);
            a2 += __shfl_xor(a2, off, 64);
            a3 += __shfl_xor(a3, off, 64);
        }
        // row L2 norm: each 16-lane group now holds the full row (4 dims/lane)
        float s = a0 * a0 + a1 * a1 + a2 * a2 + a3 * a3;
        #pragma unroll
        for (int off = 1; off < 16; off <<= 1)
            s += __shfl_xor(s, off, 64);
        float inv = 1.0f / fmaxf(sqrtf(s), EPS);
        float w = ((g == 0) ? w0 : (g == 1) ? w1 : w2) / ws * inv;
        r0 += w * a0; r1 += w * a1; r2 += w * a2; r3 += w * a3;
    }

    if (sub == 0) {
        float4 o = make_float4(r0, r1, r2, r3);
        *(float4*)(out + (long)row * DIM + li * 4) = o;
    }
}

extern "C" void kernel_launch(void* const* d_in, const int* in_sizes, int n_in,
                              void* d_out, int out_size, void* d_ws, size_t ws_size,
                              hipStream_t stream) {
    const float* x     = (const float*)d_in[0];
    const float* alpha = (const float*)d_in[1];
    const int* e0 = (const int*)d_in[2];
    const int* e1 = (const int*)d_in[3];
    const int* e2 = (const int*)d_in[4];
    float* out = (float*)d_out;

    // workspace layout (~41 MB)
    ushort_t* xn   = (ushort_t*)d_ws;                          // 50000*64 bf16   (6.4 MB)
    ushort_t* bufA = xn + (long)NUM_NODES * DIM;               // 150000*64 bf16  (19.2 MB)
    float* dinv    = (float*)(bufA + (long)TOT_NODES * DIM);   // 150000 f32
    int* row_start = (int*)(dinv + TOT_NODES);                 // 150001 (pad to 150016)
    int* bhist     = row_start + 150016;                       // 640
    int* bbase     = bhist + 640;                              // 640 (TB+1 used)
    int* bcur      = bbase + 640;                              // 640
    uint_t* part   = (uint_t*)(bcur + 640);                    // 2400000 u32     (9.6 MB)
    ushort_t* esort = (ushort_t*)(part + TOT_EDGES);           // 2400000 u16     (4.8 MB)

    const int wave_grid = (NUM_NODES * 64 + 255) / 256;        // 1 wave/row, 4 waves/block

    // normalize input once (f32 -> bf16 shared table)
    l2norm_kernel<<<wave_grid, 256, 0, stream>>>(x, xn);

    // ---- build concatenated CSR via 2-pass bucketed counting sort ----
    hipMemsetAsync(bhist, 0, TB * sizeof(int), stream);
    {
        dim3 grd(P3_BLOCKS, NUM_GRAPHS);
        hist_coarse_kernel<<<grd, 256, 0, stream>>>(e0, e1, e2, bhist);
    }
    bucket_scan_kernel<<<1, 1024, 0, stream>>>(bhist, bbase, bcur);
    {
        dim3 grd(P3_BLOCKS, NUM_GRAPHS);
        partition_kernel<<<grd, 256, 0, stream>>>(e0, e1, e2, bcur, part);
    }
    bucket_sort_kernel<<<TB, 256, 0, stream>>>(part, bbase, esort, row_start, dinv);

    // ---- layer 1 (2D grid: row x graph) ----
    {
        dim3 grd(wave_grid, NUM_GRAPHS);
        conv1_all_kernel<<<grd, 256, 0, stream>>>(xn, esort, row_start, dinv, bufA);
    }
    // ---- layer 2 + normalize + blend (all graphs) ----
    conv2_finalize_kernel<<<wave_grid, 256, 0, stream>>>(bufA, esort, row_start, alpha, out);
}

// Round 7
// 255.818 us; speedup vs baseline: 1.9732x; 1.0586x over previous
//
#include <hip/hip_runtime.h>
#include <hip/hip_bf16.h>

#define NUM_NODES 50000
#define DIM 64
#define NUM_EDGES 800000
#define NUM_GRAPHS 3
#define TOT_NODES (NUM_NODES * NUM_GRAPHS)      // 150000
#define TOT_EDGES (NUM_EDGES * NUM_GRAPHS)      // 2400000
#define EPS 1e-12f

#define NB 196                                   // buckets per graph: dst>>8
#define TB (NB * NUM_GRAPHS)                     // 588 total buckets
#define P3_CHUNK 8192
#define P3_BLOCKS ((NUM_EDGES + P3_CHUNK - 1) / P3_CHUNK)   // 98
#define P4_CAP 6144                              // max records per bucket (mean 4096)

typedef unsigned short ushort_t;
typedef unsigned int uint_t;
typedef unsigned short ushort8v __attribute__((ext_vector_type(8)));   // 16 B

__device__ __forceinline__ float bf2f(ushort_t u) {
    return __uint_as_float(((uint_t)u) << 16);
}
__device__ __forceinline__ ushort_t f2bf(float f) {
    uint_t x = __float_as_uint(f);
    uint_t r = (x + 0x7FFFu + ((x >> 16) & 1u)) >> 16;   // RNE
    return (ushort_t)r;
}

// ---------------- L2 normalize input -> bf16 shared table ----------------
__global__ void l2norm_kernel(const float* __restrict__ in, ushort_t* __restrict__ out) {
    int row = blockIdx.x * (blockDim.x >> 6) + (threadIdx.x >> 6);
    int lane = threadIdx.x & 63;
    if (row >= NUM_NODES) return;
    float v = in[(long)row * DIM + lane];
    float s = v * v;
    #pragma unroll
    for (int off = 32; off > 0; off >>= 1)
        s += __shfl_xor(s, off, 64);
    float inv = 1.0f / fmaxf(sqrtf(s), EPS);
    out[(long)row * DIM + lane] = f2bf(v * inv);
}

// ---------------- P1: coarse histogram (LDS-binned) ----------------
__global__ void hist_coarse_kernel(const int* __restrict__ e0, const int* __restrict__ e1,
                                   const int* __restrict__ e2, int* __restrict__ bhist) {
    int g = blockIdx.y;
    const int* dst = ((g == 0) ? e0 : (g == 1) ? e1 : e2) + NUM_EDGES;
    __shared__ int h[NB];
    int t = threadIdx.x;
    for (int i = t; i < NB; i += 256) h[i] = 0;
    __syncthreads();
    int base = blockIdx.x * P3_CHUNK;
    int n = min(P3_CHUNK, NUM_EDGES - base);
    for (int i = t; i < n; i += 256)
        atomicAdd(&h[dst[base + i] >> 8], 1);
    __syncthreads();
    for (int i = t; i < NB; i += 256)
        if (h[i]) atomicAdd(&bhist[g * NB + i], h[i]);
}

// ---------------- P2: exclusive-scan 588 bucket counts (1 block) ----------------
__global__ void bucket_scan_kernel(const int* __restrict__ bhist, int* __restrict__ bbase,
                                   int* __restrict__ bcur) {
    int t = threadIdx.x;
    int v = (t < TB) ? bhist[t] : 0;
    __shared__ int sd[1024];
    sd[t] = v;
    __syncthreads();
    #pragma unroll
    for (int off = 1; off < 1024; off <<= 1) {
        int add = (t >= off) ? sd[t - off] : 0;
        __syncthreads();
        sd[t] += add;
        __syncthreads();
    }
    if (t < TB) {
        int ex = sd[t] - v;
        bbase[t] = ex;
        bcur[t] = ex;
    }
    if (t == 0) bbase[TB] = TOT_EDGES;
}

// ---------------- P3: partition edges into buckets, LDS-staged coalesced writes ----------------
__global__ void partition_kernel(const int* __restrict__ e0, const int* __restrict__ e1,
                                 const int* __restrict__ e2,
                                 int* __restrict__ bcur, uint_t* __restrict__ part) {
    __shared__ uint_t recs[P3_CHUNK];        // 32 KB
    __shared__ int h[NB], lstart[NB], gbase[NB], lcur[NB];
    __shared__ int sc[256];

    int g = blockIdx.y;
    const int* ei = (g == 0) ? e0 : (g == 1) ? e1 : e2;
    const int* srcp = ei;
    const int* dstp = ei + NUM_EDGES;
    int base = blockIdx.x * P3_CHUNK;
    int n = min(P3_CHUNK, NUM_EDGES - base);
    int t = threadIdx.x;

    for (int i = t; i < NB; i += 256) h[i] = 0;
    __syncthreads();
    for (int i = t; i < n; i += 256)
        atomicAdd(&h[dstp[base + i] >> 8], 1);
    __syncthreads();

    // block scan over NB (<=256) with 256 threads
    {
        int v = (t < NB) ? h[t] : 0;
        sc[t] = v;
        __syncthreads();
        #pragma unroll
        for (int off = 1; off < 256; off <<= 1) {
            int add = (t >= off) ? sc[t - off] : 0;
            __syncthreads();
            sc[t] += add;
            __syncthreads();
        }
        if (t < NB) {
            int ex = sc[t] - v;
            lstart[t] = ex;
            lcur[t] = ex;
            gbase[t] = (v > 0) ? atomicAdd(&bcur[g * NB + t], v) : 0;
        }
    }
    __syncthreads();

    // place records into LDS, bucket-sorted
    for (int i = t; i < n; i += 256) {
        int s = srcp[base + i];
        int d = dstp[base + i];
        int pos = atomicAdd(&lcur[d >> 8], 1);
        recs[pos] = ((uint_t)d << 16) | (uint_t)s;
    }
    __syncthreads();

    // stream out: consecutive LDS slots -> consecutive global slots per bucket segment
    for (int i = t; i < n; i += 256) {
        uint_t r = recs[i];
        int b = r >> 24;                      // dst>>8 (dst < 2^16)
        part[gbase[b] + (i - lstart[b])] = r;
    }
}

// ---------------- P4: per-bucket fine sort -> esort + row_start + dinv ----------------
__global__ void bucket_sort_kernel(const uint_t* __restrict__ part, const int* __restrict__ bbase,
                                   ushort_t* __restrict__ esort, int* __restrict__ row_start,
                                   float* __restrict__ dinv) {
    __shared__ uint_t recs[P4_CAP];          // 24 KB
    __shared__ int rstart[256], lcur[256];
    __shared__ int sc[256];

    int b = blockIdx.x;                       // 0..TB-1
    int g = b / NB;
    int bhi = b % NB;
    int s0 = bbase[b];
    int n = bbase[b + 1] - s0;
    int t = threadIdx.x;

    sc[t] = 0;   // histogram over dst-low
    __syncthreads();
    for (int i = t; i < n; i += 256) {
        uint_t r = part[s0 + i];
        recs[i] = r;
        atomicAdd(&sc[(r >> 16) & 255], 1);
    }
    __syncthreads();
    int v = sc[t];
    __syncthreads();
    sc[t] = v;
    __syncthreads();
    #pragma unroll
    for (int off = 1; off < 256; off <<= 1) {
        int add = (t >= off) ? sc[t - off] : 0;
        __syncthreads();
        sc[t] += add;
        __syncthreads();
    }
    int ex = sc[t] - v;
    rstart[t] = ex;
    lcur[t] = ex;

    int node = (bhi << 8) + t;
    if (node < NUM_NODES) {
        row_start[g * NUM_NODES + node] = s0 + ex;
        dinv[g * NUM_NODES + node] = (v > 0) ? rsqrtf((float)v) : 0.0f;
    }
    if (b == TB - 1 && t == 0) row_start[TOT_NODES] = TOT_EDGES;
    __syncthreads();

    for (int i = t; i < n; i += 256) {
        uint_t r = recs[i];
        int dl = (r >> 16) & 255;
        int pos = atomicAdd(&lcur[dl], 1);
        esort[s0 + pos] = (ushort_t)(r & 0xFFFFu);
    }
}

// ---------------- layer 1, 2D grid (row, g): b[t] = dinv_t^2 * sum dinv_s * xn[s] ----------------
// 8 lanes per row (ushort8 = 16 B/lane); 8 edges in flight per wave, unroll x2 -> 16.
__global__ void conv1_all_kernel(const ushort_t* __restrict__ xn,
                                 const ushort_t* __restrict__ esort,
                                 const int* __restrict__ row_start,
                                 const float* __restrict__ dinv,
                                 ushort_t* __restrict__ bufA) {
    int row = blockIdx.x * (blockDim.x >> 6) + (threadIdx.x >> 6);
    int g = blockIdx.y;
    int lane = threadIdx.x & 63;
    int sub = lane >> 3;          // 0..7: which edge of the group
    int li  = lane & 7;           // 0..7: dims [li*8, li*8+8)
    if (row >= NUM_NODES) return;

    int k = g * NUM_NODES + row;
    int start = __builtin_amdgcn_readfirstlane(row_start[k]);
    int end   = __builtin_amdgcn_readfirstlane(row_start[k + 1]);
    const float* dv = dinv + g * NUM_NODES;

    float a[8];
    #pragma unroll
    for (int j = 0; j < 8; ++j) a[j] = 0.0f;

    int i = start;
    for (; i + 16 <= end; i += 16) {
        int sA = esort[i + sub];
        int sB = esort[i + 8 + sub];
        float dA = dv[sA];
        float dB = dv[sB];
        ushort8v rA = *(const ushort8v*)(xn + (long)sA * DIM + li * 8);
        ushort8v rB = *(const ushort8v*)(xn + (long)sB * DIM + li * 8);
        #pragma unroll
        for (int j = 0; j < 8; ++j) a[j] += dA * bf2f(rA[j]);
        #pragma unroll
        for (int j = 0; j < 8; ++j) a[j] += dB * bf2f(rB[j]);
    }
    for (; i < end; i += 8) {
        int e = i + sub;
        if (e < end) {
            int s = esort[e];
            float d = dv[s];
            ushort8v r = *(const ushort8v*)(xn + (long)s * DIM + li * 8);
            #pragma unroll
            for (int j = 0; j < 8; ++j) a[j] += d * bf2f(r[j]);
        }
    }
    // combine the 8 sub-groups (dims aligned across subs)
    #pragma unroll
    for (int off = 8; off < 64; off <<= 1) {
        #pragma unroll
        for (int j = 0; j < 8; ++j)
            a[j] += __shfl_xor(a[j], off, 64);
    }
    float dt = dinv[k];
    float sc = dt * dt;
    if (sub == 0) {
        ushort8v o;
        #pragma unroll
        for (int j = 0; j < 8; ++j) o[j] = f2bf(a[j] * sc);
        *(ushort8v*)(bufA + (long)k * DIM + li * 8) = o;
    }
}

// ---------------- layer 2 (pure sum) + l2norm + weighted blend -> out ----------------
__global__ void conv2_finalize_kernel(const ushort_t* __restrict__ bufA,
                                      const ushort_t* __restrict__ esort,
                                      const int* __restrict__ row_start,
                                      const float* __restrict__ alpha,
                                      float* __restrict__ out) {
    int row = blockIdx.x * (blockDim.x >> 6) + (threadIdx.x >> 6);
    int lane = threadIdx.x & 63;
    int sub = lane >> 3;
    int li  = lane & 7;
    if (row >= NUM_NODES) return;

    // softmax(alpha) -> clip -> renormalize
    float al0 = alpha[0], al1 = alpha[1], al2 = alpha[2];
    float m = fmaxf(al0, fmaxf(al1, al2));
    float e0 = expf(al0 - m), e1 = expf(al1 - m), e2 = expf(al2 - m);
    float es = e0 + e1 + e2;
    float w0 = fmaxf(e0 / es, 1e-4f);
    float w1 = fmaxf(e1 / es, 1e-4f);
    float w2 = fmaxf(e2 / es, 1e-4f);
    float ws = w0 + w1 + w2;

    float r[8];
    #pragma unroll
    for (int j = 0; j < 8; ++j) r[j] = 0.0f;

    #pragma unroll
    for (int g = 0; g < NUM_GRAPHS; ++g) {
        int k = g * NUM_NODES + row;
        int start = __builtin_amdgcn_readfirstlane(row_start[k]);
        int end   = __builtin_amdgcn_readfirstlane(row_start[k + 1]);
        const ushort_t* tbl = bufA + (long)g * NUM_NODES * DIM;

        float a[8];
        #pragma unroll
        for (int j = 0; j < 8; ++j) a[j] = 0.0f;

        int i = start;
        for (; i + 16 <= end; i += 16) {
            int sA = esort[i + sub];
            int sB = esort[i + 8 + sub];
            ushort8v rA = *(const ushort8v*)(tbl + (long)sA * DIM + li * 8);
            ushort8v rB = *(const ushort8v*)(tbl + (long)sB * DIM + li * 8);
            #pragma unroll
            for (int j = 0; j < 8; ++j) a[j] += bf2f(rA[j]);
            #pragma unroll
            for (int j = 0; j < 8; ++j) a[j] += bf2f(rB[j]);
        }
        for (; i < end; i += 8) {
            int e = i + sub;
            if (e < end) {
                int s = esort[e];
                ushort8v rr = *(const ushort8v*)(tbl + (long)s * DIM + li * 8);
                #pragma unroll
                for (int j = 0; j < 8; ++j) a[j] += bf2f(rr[j]);
            }
        }
        #pragma unroll
        for (int off = 8; off < 64; off <<= 1) {
            #pragma unroll
            for (int j = 0; j < 8; ++j)
                a[j] += __shfl_xor(a[j], off, 64);
        }
        // row L2 norm: each 8-lane group holds the full row (8 dims/lane)
        float s = 0.0f;
        #pragma unroll
        for (int j = 0; j < 8; ++j) s += a[j] * a[j];
        #pragma unroll
        for (int off = 1; off < 8; off <<= 1)
            s += __shfl_xor(s, off, 64);
        float inv = 1.0f / fmaxf(sqrtf(s), EPS);
        float w = ((g == 0) ? w0 : (g == 1) ? w1 : w2) / ws * inv;
        #pragma unroll
        for (int j = 0; j < 8; ++j) r[j] += w * a[j];
    }

    if (sub == 0) {
        float4 o0 = make_float4(r[0], r[1], r[2], r[3]);
        float4 o1 = make_float4(r[4], r[5], r[6], r[7]);
        float* p = out + (long)row * DIM + li * 8;
        *(float4*)p = o0;
        *(float4*)(p + 4) = o1;
    }
}

extern "C" void kernel_launch(void* const* d_in, const int* in_sizes, int n_in,
                              void* d_out, int out_size, void* d_ws, size_t ws_size,
                              hipStream_t stream) {
    const float* x     = (const float*)d_in[0];
    const float* alpha = (const float*)d_in[1];
    const int* e0 = (const int*)d_in[2];
    const int* e1 = (const int*)d_in[3];
    const int* e2 = (const int*)d_in[4];
    float* out = (float*)d_out;

    // workspace layout (~41 MB)
    ushort_t* xn   = (ushort_t*)d_ws;                          // 50000*64 bf16   (6.4 MB)
    ushort_t* bufA = xn + (long)NUM_NODES * DIM;               // 150000*64 bf16  (19.2 MB)
    float* dinv    = (float*)(bufA + (long)TOT_NODES * DIM);   // 150000 f32
    int* row_start = (int*)(dinv + TOT_NODES);                 // 150001 (pad to 150016)
    int* bhist     = row_start + 150016;                       // 640
    int* bbase     = bhist + 640;                              // 640 (TB+1 used)
    int* bcur      = bbase + 640;                              // 640
    uint_t* part   = (uint_t*)(bcur + 640);                    // 2400000 u32     (9.6 MB)
    ushort_t* esort = (ushort_t*)(part + TOT_EDGES);           // 2400000 u16     (4.8 MB)

    const int wave_grid = (NUM_NODES * 64 + 255) / 256;        // 1 wave/row, 4 waves/block

    // normalize input once (f32 -> bf16 shared table)
    l2norm_kernel<<<wave_grid, 256, 0, stream>>>(x, xn);

    // ---- build concatenated CSR via 2-pass bucketed counting sort ----
    hipMemsetAsync(bhist, 0, TB * sizeof(int), stream);
    {
        dim3 grd(P3_BLOCKS, NUM_GRAPHS);
        hist_coarse_kernel<<<grd, 256, 0, stream>>>(e0, e1, e2, bhist);
    }
    bucket_scan_kernel<<<1, 1024, 0, stream>>>(bhist, bbase, bcur);
    {
        dim3 grd(P3_BLOCKS, NUM_GRAPHS);
        partition_kernel<<<grd, 256, 0, stream>>>(e0, e1, e2, bcur, part);
    }
    bucket_sort_kernel<<<TB, 256, 0, stream>>>(part, bbase, esort, row_start, dinv);

    // ---- layer 1 (2D grid: row x graph) ----
    {
        dim3 grd(wave_grid, NUM_GRAPHS);
        conv1_all_kernel<<<grd, 256, 0, stream>>>(xn, esort, row_start, dinv, bufA);
    }
    // ---- layer 2 + normalize + blend (all graphs) ----
    conv2_finalize_kernel<<<wave_grid, 256, 0, stream>>>(bufA, esort, row_start, alpha, out);
}